// Round 15
// baseline (72.684 us; speedup 1.0000x reference)
//
#include <hip/hip_runtime.h>

#define S_TOK 8192
#define NB 8
#define HQ 32
#define HKV 8
#define DH 128
#define KK 128
#define DIM 4096
#define NCOL4 (DIM / 4)   // 1024

// ---------------- GEMV core: 4 rows per block, 256 threads (verbatim R11/R14) ----------------
__device__ __forceinline__ void gemv4(const float* __restrict__ W,
                                      const float* __restrict__ x,
                                      float* __restrict__ y,
                                      int r0, int t, float* red /* [4][32] */) {
    const float4* wp0 = (const float4*)(W + (size_t)(r0 + 0) * DIM);
    const float4* wp1 = (const float4*)(W + (size_t)(r0 + 1) * DIM);
    const float4* wp2 = (const float4*)(W + (size_t)(r0 + 2) * DIM);
    const float4* wp3 = (const float4*)(W + (size_t)(r0 + 3) * DIM);
    const float4* x4 = (const float4*)x;
    float acc0[NB], acc1[NB], acc2[NB], acc3[NB];
#pragma unroll
    for (int b = 0; b < NB; ++b) { acc0[b] = 0.f; acc1[b] = 0.f; acc2[b] = 0.f; acc3[b] = 0.f; }
#pragma unroll
    for (int it = 0; it < 4; ++it) {
        const int c = t + it * 256;
        float4 w0 = wp0[c];
        float4 w1 = wp1[c];
        float4 w2 = wp2[c];
        float4 w3 = wp3[c];
#pragma unroll
        for (int b = 0; b < NB; ++b) {
            float4 xv = x4[(size_t)b * NCOL4 + c];
            acc0[b] += w0.x * xv.x + w0.y * xv.y + w0.z * xv.z + w0.w * xv.w;
            acc1[b] += w1.x * xv.x + w1.y * xv.y + w1.z * xv.z + w1.w * xv.w;
            acc2[b] += w2.x * xv.x + w2.y * xv.y + w2.z * xv.z + w2.w * xv.w;
            acc3[b] += w3.x * xv.x + w3.y * xv.y + w3.z * xv.z + w3.w * xv.w;
        }
    }
    const int lane = t & 63, wv = t >> 6;
#pragma unroll
    for (int b = 0; b < NB; ++b) {
#pragma unroll
        for (int o = 32; o > 0; o >>= 1) {
            acc0[b] += __shfl_down(acc0[b], o);
            acc1[b] += __shfl_down(acc1[b], o);
            acc2[b] += __shfl_down(acc2[b], o);
            acc3[b] += __shfl_down(acc3[b], o);
        }
    }
    if (lane == 0) {
#pragma unroll
        for (int b = 0; b < NB; ++b) {
            red[wv * 32 + 0 * 8 + b] = acc0[b];
            red[wv * 32 + 1 * 8 + b] = acc1[b];
            red[wv * 32 + 2 * 8 + b] = acc2[b];
            red[wv * 32 + 3 * 8 + b] = acc3[b];
        }
    }
    __syncthreads();
    if (t < 32) {
        float s = red[0 * 32 + t] + red[1 * 32 + t] + red[2 * 32 + t] + red[3 * 32 + t];
        int b = t & 7;
        int r = r0 + (t >> 3);
        y[(size_t)b * DIM + r] = s;
    }
}

// ---------------- Kernel 1: fused { impbits (blk 0..255) | Wq GEMV 4-row (blk 256..1279) } --
// (verbatim R11/R14)
__global__ __launch_bounds__(256) void imp_gemvq_kernel(const float* __restrict__ attn_w,
                                                        const float* __restrict__ Wq,
                                                        const float* __restrict__ hidden,
                                                        unsigned* __restrict__ impbits,
                                                        float* __restrict__ q) {
    __shared__ float redg[4 * 32];
    const int t = threadIdx.x;
    const int bl = blockIdx.x;

    if (bl < 256) {
        const int tok = bl * 256 + t;              // covers NB*S_TOK = 65536
        const int b = tok >> 13;                   // /8192
        const int s = tok & (S_TOK - 1);
        const float* p = attn_w + (size_t)b * HQ * S_TOK + s;
        float acc = 0.f;
#pragma unroll
        for (int h = 0; h < HQ; ++h) acc += p[(size_t)h * S_TOK];
        unsigned uu = __float_as_uint(acc * (1.0f / 32.0f));
        uu = (uu & 0x80000000u) ? ~uu : (uu | 0x80000000u);   // monotone map
        impbits[tok] = uu;
        return;
    }
    gemv4(Wq, hidden, q, (bl - 256) * 4, t, redg);
}

// ---------------- Kernel 2: attn512 with in-block top-k (R14 + XCD-locality swizzle) ----
// NEW vs R14: block->(b,h) mapping remapped so bl % 8 == b. Under round-robin
// blockIdx->XCD dispatch, ALL 32 blocks of batch b land on XCD b: the batch's
// 32 KB impbits slice and every gathered K/V row is fetched into that XCD's L2
// once and L2-hit by all sharers (was: 4 heads sharing a kvh slice spread over
// 4 XCDs, each re-fetching via L3). Pure index permutation — math unchanged.
__global__ __launch_bounds__(512) void attn_topk_kernel(const unsigned* __restrict__ impbits,
                                                        const float* __restrict__ q,
                                                        const float* __restrict__ k,
                                                        const float* __restrict__ v,
                                                        float* __restrict__ ctx,
                                                        float* __restrict__ probs_out) {
    __shared__ __align__(16) unsigned mb[S_TOK];   // 32 KB
    __shared__ __align__(16) int hist[256];        // radix hist; reused as sorted idx
    __shared__ unsigned sprefix;
    __shared__ int skrem;
    __shared__ int nsel;
    __shared__ unsigned selb[KK];
    __shared__ int seli[KK];
    __shared__ float qs[DH];
    __shared__ float scs[KK];
    __shared__ float ps[KK];
    __shared__ float red2[2];
    __shared__ float red3[2];
    __shared__ float part[3][DH];

    const int t = threadIdx.x;   // 512 threads
    const int bl = blockIdx.x;
    // XCD-locality mapping: bl = xcd + 8*(kvh*4 + lane4); b = xcd; h = kvh*4 + lane4.
    // Bijection over [0,256): every (b,h) produced exactly once; bl % 8 == b.
    const int xcd = bl & 7, slot = bl >> 3;
    const int b = xcd;
    const int kvh = slot >> 2;
    const int h = kvh * 4 + (slot & 3);

    if (t < DH) qs[t] = q[(size_t)(b * HQ + h) * DH + t] * 0.088388347648318447f; // 1/sqrt(128)

    // ---- stage mapped bits for this batch ----
    const unsigned* ip = impbits + (size_t)b * S_TOK;
    for (int i = t; i < S_TOK; i += 512) mb[i] = ip[i];
    if (t == 0) { sprefix = 0u; skrem = KK; nsel = 0; }
    __syncthreads();

    // ---- radix-256 select (R5-verified 512-thread code) ----
    for (int shift = 24; shift >= 0; shift -= 8) {
        if (t < 256) hist[t] = 0;
        __syncthreads();
        const unsigned pfx = sprefix;
        const int krem = skrem;
        if (shift == 24) {
            // values cluster into few exponent bins -> ballot-aggregate
            for (int i = t; i < S_TOK; i += 512) {
                int bin = mb[i] >> 24;
                unsigned long long rem = __ballot(1);
                while (rem) {
                    int fl = (int)__builtin_ctzll(rem);
                    int fbin = __shfl(bin, fl);
                    unsigned long long match = __ballot(bin == fbin);
                    if ((t & 63) == fl) atomicAdd(&hist[fbin], (int)__popcll(match));
                    rem &= ~match;
                }
            }
        } else {
            const unsigned pmask = 0xFFFFFFFFu << (shift + 8);
            for (int i = t; i < S_TOK; i += 512) {
                unsigned u = mb[i];
                if ((u & pmask) == pfx) atomicAdd(&hist[(u >> shift) & 255], 1);
            }
        }
        __syncthreads();
        // wave 0: parallel descending-bin scan
        if (t < 64) {
            int4 h4 = *(const int4*)&hist[252 - 4 * t];
            int h0 = h4.w, h1 = h4.z, h2 = h4.y, h3 = h4.x;   // descending-bin order
            int c0 = h0, c1 = c0 + h1, c2 = c1 + h2, c3 = c2 + h3;
            int inc = c3;
#pragma unroll
            for (int o = 1; o < 64; o <<= 1) {
                int yv = __shfl_up(inc, o);
                if (t >= o) inc += yv;
            }
            int excl = inc - c3;
            int cand = -1, before = 0;
            if      (excl + c0 >= krem) { cand = 0; before = excl; }
            else if (excl + c1 >= krem) { cand = 1; before = excl + c0; }
            else if (excl + c2 >= krem) { cand = 2; before = excl + c1; }
            else if (excl + c3 >= krem) { cand = 3; before = excl + c2; }
            unsigned long long ball = __ballot(cand >= 0);
            int win = (int)__builtin_ctzll(ball);
            if (t == win) {
                int p = 4 * t + cand;
                sprefix = pfx | ((unsigned)(255 - p) << shift);
                skrem = krem - before;
            }
        }
        __syncthreads();
    }
    const unsigned T = sprefix;

    // collect strictly-greater (unordered; ordered by rank below)
    for (int i = t; i < S_TOK; i += 512) {
        unsigned u = mb[i];
        if (u > T) {
            int p = atomicAdd(&nsel, 1);
            selb[p] = u; seli[p] = i;
        }
    }
    __syncthreads();
    const int g = nsel;
    const int r = KK - g;          // >= 1 by construction

    // wave 0: ordered scan collects the r smallest-index ties
    if (t < 64) {
        int found = 0;
        for (int base0 = 0; base0 < S_TOK && found < r; base0 += 64) {
            bool is_tie = (mb[base0 + t] == T);
            unsigned long long ball = __ballot(is_tie);
            int pos = (int)__popcll(ball & ((1ull << t) - 1ull));
            if (is_tie && found + pos < r) {
                selb[g + found + pos] = T;
                seli[g + found + pos] = base0 + t;
            }
            found += (int)__popcll(ball);
        }
    }
    __syncthreads();

    // rank-order sort (R14-verified): strict total order (value desc, index asc)
    // -> rank is a permutation of 0..127. hist[] reused as the sorted index array.
    if (t < KK) {
        const unsigned myv = selb[t];
        const int myi = seli[t];
        int rank = 0;
#pragma unroll 4
        for (int j = 0; j < KK; ++j) {
            unsigned vj = selb[j];          // LDS broadcast (uniform j across lanes)
            int ij = seli[j];
            if (vj > myv || (vj == myv && ij < myi)) ++rank;
        }
        hist[rank] = myi;
    }
    __syncthreads();
    // hist[0..127] = topk indices for this batch (value desc, index asc)

    // ---- attention (R8-verified attn512, idxs := hist) ----
    {
        const int tok = t >> 2, qpart = t & 3;
        const float4* k4 = (const float4*)(k +
            ((size_t)(b * HKV + kvh) * S_TOK + hist[tok]) * DH + qpart * 32);
        float sc = 0.f;
#pragma unroll
        for (int d4 = 0; d4 < 8; ++d4) {
            float4 kv = k4[d4];
            int d0 = qpart * 32 + d4 * 4;
            sc += qs[d0] * kv.x + qs[d0 + 1] * kv.y + qs[d0 + 2] * kv.z + qs[d0 + 3] * kv.w;
        }
        sc += __shfl_xor(sc, 1);
        sc += __shfl_xor(sc, 2);
        if (qpart == 0) scs[tok] = sc;
    }
    __syncthreads();

    float sc = (t < KK) ? scs[t] : -3.4e38f;
    if (t < KK) {
        float m = sc;
        for (int o = 32; o > 0; o >>= 1) m = fmaxf(m, __shfl_down(m, o));
        if ((t & 63) == 0) red2[t >> 6] = m;
    }
    __syncthreads();
    const float mx = fmaxf(red2[0], red2[1]);
    float p = 0.f;
    if (t < KK) {
        p = expf(sc - mx);
        float sm = p;
        for (int o = 32; o > 0; o >>= 1) sm += __shfl_down(sm, o);
        if ((t & 63) == 0) red3[t >> 6] = sm;
    }
    __syncthreads();
    if (t < KK) {
        p /= (red3[0] + red3[1]);
        ps[t] = p;
        probs_out[(size_t)(b * HQ + h) * KK + t] = p;
    }
    __syncthreads();

    // PV: 4 groups x 128 dims, 32 tokens per group, LDS combine
    {
        const int d = t & (DH - 1), grp = t >> 7;
        const float* vbase = v + (size_t)(b * HKV + kvh) * S_TOK * DH;
        float acc = 0.f;
        const int s0 = grp * 32;
#pragma unroll 4
        for (int s2 = s0; s2 < s0 + 32; ++s2) {
            acc += ps[s2] * vbase[(size_t)hist[s2] * DH + d];
        }
        if (grp) part[grp - 1][d] = acc;
        __syncthreads();
        if (grp == 0)
            ctx[(size_t)(b * HQ + h) * DH + d] = acc + part[0][d] + part[1][d] + part[2][d];
    }
}

// ---------------- Kernel 3: Wo GEMV, 4 rows per block (verbatim R11/R14) ----------------
__global__ __launch_bounds__(256) void gemv_wo_kernel(const float* __restrict__ Wo,
                                                      const float* __restrict__ ctx,
                                                      float* __restrict__ out) {
    __shared__ float redg[4 * 32];
    gemv4(Wo, ctx, out, blockIdx.x * 4, threadIdx.x, redg);
}

// ---------------- launcher: 3 launches, no spin, no memset (verbatim R11/R14) ----------------
extern "C" void kernel_launch(void* const* d_in, const int* in_sizes, int n_in,
                              void* d_out, int out_size, void* d_ws, size_t ws_size,
                              hipStream_t stream) {
    const float* hidden = (const float*)d_in[0];   // [8,1,4096]
    const float* attn_w = (const float*)d_in[1];   // [8,32,1,8192]
    const float* k      = (const float*)d_in[2];   // [8,8,8192,128]
    const float* v      = (const float*)d_in[3];   // [8,8,8192,128]
    const float* Wq     = (const float*)d_in[4];   // [4096,4096]
    const float* Wo     = (const float*)d_in[5];   // [4096,4096]

    float* out   = (float*)d_out;                  // [8,4096]
    float* probs = out + NB * DIM;                 // [8,32,1,128]

    char* ws = (char*)d_ws;
    unsigned* impbits = (unsigned*)ws;              // 8*8192*4 = 262144 B
    float* q     = (float*)(ws + 262144);           // 8*4096*4 = 131072 B
    float* ctx   = (float*)(ws + 393216);           // 8*4096*4 = 131072 B

    // L1: blocks 0..255 impbits; 256..1279 Wq GEMV (4 rows/block; independent halves)
    imp_gemvq_kernel<<<256 + DIM / 4, 256, 0, stream>>>(attn_w, Wq, hidden, impbits, q);
    // L2: per-(b,h) block (XCD-locality swizzled): in-block topk + attn512
    attn_topk_kernel<<<NB * HQ, 512, 0, stream>>>(impbits, q, k, v, ctx, probs);
    // L3: Wo GEMV (4 rows/block)
    gemv_wo_kernel<<<DIM / 4, 256, 0, stream>>>(Wo, ctx, out);
}

// Round 16
// 70.674 us; speedup vs baseline: 1.0284x; 1.0284x over previous
//
#include <hip/hip_runtime.h>

#define S_TOK 8192
#define NB 8
#define HQ 32
#define HKV 8
#define DH 128
#define KK 128
#define DIM 4096
#define NCOL4 (DIM / 4)   // 1024

// ---------------- GEMV core: 4 rows per block, 256 threads (verbatim R11/R14) ----------------
__device__ __forceinline__ void gemv4(const float* __restrict__ W,
                                      const float* __restrict__ x,
                                      float* __restrict__ y,
                                      int r0, int t, float* red /* [4][32] */) {
    const float4* wp0 = (const float4*)(W + (size_t)(r0 + 0) * DIM);
    const float4* wp1 = (const float4*)(W + (size_t)(r0 + 1) * DIM);
    const float4* wp2 = (const float4*)(W + (size_t)(r0 + 2) * DIM);
    const float4* wp3 = (const float4*)(W + (size_t)(r0 + 3) * DIM);
    const float4* x4 = (const float4*)x;
    float acc0[NB], acc1[NB], acc2[NB], acc3[NB];
#pragma unroll
    for (int b = 0; b < NB; ++b) { acc0[b] = 0.f; acc1[b] = 0.f; acc2[b] = 0.f; acc3[b] = 0.f; }
#pragma unroll
    for (int it = 0; it < 4; ++it) {
        const int c = t + it * 256;
        float4 w0 = wp0[c];
        float4 w1 = wp1[c];
        float4 w2 = wp2[c];
        float4 w3 = wp3[c];
#pragma unroll
        for (int b = 0; b < NB; ++b) {
            float4 xv = x4[(size_t)b * NCOL4 + c];
            acc0[b] += w0.x * xv.x + w0.y * xv.y + w0.z * xv.z + w0.w * xv.w;
            acc1[b] += w1.x * xv.x + w1.y * xv.y + w1.z * xv.z + w1.w * xv.w;
            acc2[b] += w2.x * xv.x + w2.y * xv.y + w2.z * xv.z + w2.w * xv.w;
            acc3[b] += w3.x * xv.x + w3.y * xv.y + w3.z * xv.z + w3.w * xv.w;
        }
    }
    const int lane = t & 63, wv = t >> 6;
#pragma unroll
    for (int b = 0; b < NB; ++b) {
#pragma unroll
        for (int o = 32; o > 0; o >>= 1) {
            acc0[b] += __shfl_down(acc0[b], o);
            acc1[b] += __shfl_down(acc1[b], o);
            acc2[b] += __shfl_down(acc2[b], o);
            acc3[b] += __shfl_down(acc3[b], o);
        }
    }
    if (lane == 0) {
#pragma unroll
        for (int b = 0; b < NB; ++b) {
            red[wv * 32 + 0 * 8 + b] = acc0[b];
            red[wv * 32 + 1 * 8 + b] = acc1[b];
            red[wv * 32 + 2 * 8 + b] = acc2[b];
            red[wv * 32 + 3 * 8 + b] = acc3[b];
        }
    }
    __syncthreads();
    if (t < 32) {
        float s = red[0 * 32 + t] + red[1 * 32 + t] + red[2 * 32 + t] + red[3 * 32 + t];
        int b = t & 7;
        int r = r0 + (t >> 3);
        y[(size_t)b * DIM + r] = s;
    }
}

// ---------------- Kernel 1: fused { impbits float4 (blk 0..63) | Wq GEMV 4-row (blk 64..1087) }
// Importance now uses float4 loads (R4-verified bit-exact: each component sums
// serially over h=0..31, identical adds per token). 64 blocks instead of 256 —
// 1/4 the load instructions for the same 8.4 MB.
__global__ __launch_bounds__(256) void imp_gemvq_kernel(const float* __restrict__ attn_w,
                                                        const float* __restrict__ Wq,
                                                        const float* __restrict__ hidden,
                                                        unsigned* __restrict__ impbits,
                                                        float* __restrict__ q) {
    __shared__ float redg[4 * 32];
    const int t = threadIdx.x;
    const int bl = blockIdx.x;

    if (bl < 64) {
        const int u = bl * 256 + t;                // 16384 float4-units = NB*S_TOK/4
        const int b = u >> 11;                     // 2048 units per batch
        const int base = (u & 2047) * 4;
        float4 acc = {0.f, 0.f, 0.f, 0.f};
#pragma unroll 8
        for (int h = 0; h < HQ; ++h) {
            float4 w = *(const float4*)(attn_w + (size_t)(b * HQ + h) * S_TOK + base);
            acc.x += w.x; acc.y += w.y; acc.z += w.z; acc.w += w.w;
        }
        float vals[4] = {acc.x, acc.y, acc.z, acc.w};
        unsigned ub[4];
#pragma unroll
        for (int j = 0; j < 4; ++j) {
            unsigned uu = __float_as_uint(vals[j] * (1.0f / 32.0f));
            ub[j] = (uu & 0x80000000u) ? ~uu : (uu | 0x80000000u);   // monotone map
        }
        *(uint4*)(impbits + (size_t)b * S_TOK + base) = make_uint4(ub[0], ub[1], ub[2], ub[3]);
        return;
    }
    gemv4(Wq, hidden, q, (bl - 64) * 4, t, redg);
}

// ---------------- Kernel 2: attn512 with in-block top-k (R14 + uint4 staging) ----------
__global__ __launch_bounds__(512) void attn_topk_kernel(const unsigned* __restrict__ impbits,
                                                        const float* __restrict__ q,
                                                        const float* __restrict__ k,
                                                        const float* __restrict__ v,
                                                        float* __restrict__ ctx,
                                                        float* __restrict__ probs_out) {
    __shared__ __align__(16) unsigned mb[S_TOK];   // 32 KB
    __shared__ __align__(16) int hist[256];        // radix hist; reused as sorted idx
    __shared__ unsigned sprefix;
    __shared__ int skrem;
    __shared__ int nsel;
    __shared__ unsigned selb[KK];
    __shared__ int seli[KK];
    __shared__ float qs[DH];
    __shared__ float scs[KK];
    __shared__ float ps[KK];
    __shared__ float red2[2];
    __shared__ float red3[2];
    __shared__ float part[3][DH];

    const int t = threadIdx.x;   // 512 threads
    const int bl = blockIdx.x;
    const int b = bl >> 5, h = bl & 31, kvh = h >> 2;   // R14 mapping (swizzle reverted)

    if (t < DH) qs[t] = q[(size_t)(b * HQ + h) * DH + t] * 0.088388347648318447f; // 1/sqrt(128)

    // ---- stage mapped bits for this batch (uint4 vectorized copy) ----
    {
        const uint4* ip4 = (const uint4*)(impbits + (size_t)b * S_TOK);
        uint4* mb4 = (uint4*)mb;
#pragma unroll
        for (int i = 0; i < 4; ++i) mb4[t + i * 512] = ip4[t + i * 512];
    }
    if (t == 0) { sprefix = 0u; skrem = KK; nsel = 0; }
    __syncthreads();

    // ---- radix-256 select (R5-verified 512-thread code) ----
    for (int shift = 24; shift >= 0; shift -= 8) {
        if (t < 256) hist[t] = 0;
        __syncthreads();
        const unsigned pfx = sprefix;
        const int krem = skrem;
        if (shift == 24) {
            // values cluster into few exponent bins -> ballot-aggregate
            for (int i = t; i < S_TOK; i += 512) {
                int bin = mb[i] >> 24;
                unsigned long long rem = __ballot(1);
                while (rem) {
                    int fl = (int)__builtin_ctzll(rem);
                    int fbin = __shfl(bin, fl);
                    unsigned long long match = __ballot(bin == fbin);
                    if ((t & 63) == fl) atomicAdd(&hist[fbin], (int)__popcll(match));
                    rem &= ~match;
                }
            }
        } else {
            const unsigned pmask = 0xFFFFFFFFu << (shift + 8);
            for (int i = t; i < S_TOK; i += 512) {
                unsigned u = mb[i];
                if ((u & pmask) == pfx) atomicAdd(&hist[(u >> shift) & 255], 1);
            }
        }
        __syncthreads();
        // wave 0: parallel descending-bin scan
        if (t < 64) {
            int4 h4 = *(const int4*)&hist[252 - 4 * t];
            int h0 = h4.w, h1 = h4.z, h2 = h4.y, h3 = h4.x;   // descending-bin order
            int c0 = h0, c1 = c0 + h1, c2 = c1 + h2, c3 = c2 + h3;
            int inc = c3;
#pragma unroll
            for (int o = 1; o < 64; o <<= 1) {
                int yv = __shfl_up(inc, o);
                if (t >= o) inc += yv;
            }
            int excl = inc - c3;
            int cand = -1, before = 0;
            if      (excl + c0 >= krem) { cand = 0; before = excl; }
            else if (excl + c1 >= krem) { cand = 1; before = excl + c0; }
            else if (excl + c2 >= krem) { cand = 2; before = excl + c1; }
            else if (excl + c3 >= krem) { cand = 3; before = excl + c2; }
            unsigned long long ball = __ballot(cand >= 0);
            int win = (int)__builtin_ctzll(ball);
            if (t == win) {
                int p = 4 * t + cand;
                sprefix = pfx | ((unsigned)(255 - p) << shift);
                skrem = krem - before;
            }
        }
        __syncthreads();
    }
    const unsigned T = sprefix;

    // collect strictly-greater (unordered; ordered by rank below)
    for (int i = t; i < S_TOK; i += 512) {
        unsigned u = mb[i];
        if (u > T) {
            int p = atomicAdd(&nsel, 1);
            selb[p] = u; seli[p] = i;
        }
    }
    __syncthreads();
    const int g = nsel;
    const int r = KK - g;          // >= 1 by construction

    // wave 0: ordered scan collects the r smallest-index ties
    if (t < 64) {
        int found = 0;
        for (int base0 = 0; base0 < S_TOK && found < r; base0 += 64) {
            bool is_tie = (mb[base0 + t] == T);
            unsigned long long ball = __ballot(is_tie);
            int pos = (int)__popcll(ball & ((1ull << t) - 1ull));
            if (is_tie && found + pos < r) {
                selb[g + found + pos] = T;
                seli[g + found + pos] = base0 + t;
            }
            found += (int)__popcll(ball);
        }
    }
    __syncthreads();

    // rank-order sort (R14-verified): strict total order (value desc, index asc)
    // -> rank is a permutation of 0..127. hist[] reused as the sorted index array.
    if (t < KK) {
        const unsigned myv = selb[t];
        const int myi = seli[t];
        int rank = 0;
#pragma unroll 4
        for (int j = 0; j < KK; ++j) {
            unsigned vj = selb[j];          // LDS broadcast (uniform j across lanes)
            int ij = seli[j];
            if (vj > myv || (vj == myv && ij < myi)) ++rank;
        }
        hist[rank] = myi;
    }
    __syncthreads();
    // hist[0..127] = topk indices for this batch (value desc, index asc)

    // ---- attention (R8-verified attn512, idxs := hist) ----
    {
        const int tok = t >> 2, qpart = t & 3;
        const float4* k4 = (const float4*)(k +
            ((size_t)(b * HKV + kvh) * S_TOK + hist[tok]) * DH + qpart * 32);
        float sc = 0.f;
#pragma unroll
        for (int d4 = 0; d4 < 8; ++d4) {
            float4 kv = k4[d4];
            int d0 = qpart * 32 + d4 * 4;
            sc += qs[d0] * kv.x + qs[d0 + 1] * kv.y + qs[d0 + 2] * kv.z + qs[d0 + 3] * kv.w;
        }
        sc += __shfl_xor(sc, 1);
        sc += __shfl_xor(sc, 2);
        if (qpart == 0) scs[tok] = sc;
    }
    __syncthreads();

    float sc = (t < KK) ? scs[t] : -3.4e38f;
    if (t < KK) {
        float m = sc;
        for (int o = 32; o > 0; o >>= 1) m = fmaxf(m, __shfl_down(m, o));
        if ((t & 63) == 0) red2[t >> 6] = m;
    }
    __syncthreads();
    const float mx = fmaxf(red2[0], red2[1]);
    float p = 0.f;
    if (t < KK) {
        p = expf(sc - mx);
        float sm = p;
        for (int o = 32; o > 0; o >>= 1) sm += __shfl_down(sm, o);
        if ((t & 63) == 0) red3[t >> 6] = sm;
    }
    __syncthreads();
    if (t < KK) {
        p /= (red3[0] + red3[1]);
        ps[t] = p;
        probs_out[(size_t)(b * HQ + h) * KK + t] = p;
    }
    __syncthreads();

    // PV: 4 groups x 128 dims, 32 tokens per group, LDS combine
    {
        const int d = t & (DH - 1), grp = t >> 7;
        const float* vbase = v + (size_t)(b * HKV + kvh) * S_TOK * DH;
        float acc = 0.f;
        const int s0 = grp * 32;
#pragma unroll 4
        for (int s2 = s0; s2 < s0 + 32; ++s2) {
            acc += ps[s2] * vbase[(size_t)hist[s2] * DH + d];
        }
        if (grp) part[grp - 1][d] = acc;
        __syncthreads();
        if (grp == 0)
            ctx[(size_t)(b * HQ + h) * DH + d] = acc + part[0][d] + part[1][d] + part[2][d];
    }
}

// ---------------- Kernel 3: Wo GEMV, 4 rows per block (verbatim R11/R14) ----------------
__global__ __launch_bounds__(256) void gemv_wo_kernel(const float* __restrict__ Wo,
                                                      const float* __restrict__ ctx,
                                                      float* __restrict__ out) {
    __shared__ float redg[4 * 32];
    gemv4(Wo, ctx, out, blockIdx.x * 4, threadIdx.x, redg);
}

// ---------------- launcher: 3 launches, no spin, no memset ----------------
extern "C" void kernel_launch(void* const* d_in, const int* in_sizes, int n_in,
                              void* d_out, int out_size, void* d_ws, size_t ws_size,
                              hipStream_t stream) {
    const float* hidden = (const float*)d_in[0];   // [8,1,4096]
    const float* attn_w = (const float*)d_in[1];   // [8,32,1,8192]
    const float* k      = (const float*)d_in[2];   // [8,8,8192,128]
    const float* v      = (const float*)d_in[3];   // [8,8,8192,128]
    const float* Wq     = (const float*)d_in[4];   // [4096,4096]
    const float* Wo     = (const float*)d_in[5];   // [4096,4096]

    float* out   = (float*)d_out;                  // [8,4096]
    float* probs = out + NB * DIM;                 // [8,32,1,128]

    char* ws = (char*)d_ws;
    unsigned* impbits = (unsigned*)ws;              // 8*8192*4 = 262144 B
    float* q     = (float*)(ws + 262144);           // 8*4096*4 = 131072 B
    float* ctx   = (float*)(ws + 393216);           // 8*4096*4 = 131072 B

    // L1: blocks 0..63 impbits (float4); 64..1087 Wq GEMV (4 rows/block)
    imp_gemvq_kernel<<<64 + DIM / 4, 256, 0, stream>>>(attn_w, Wq, hidden, impbits, q);
    // L2: per-(b,h) block: in-block topk (rank-order sort) + attn512
    attn_topk_kernel<<<NB * HQ, 512, 0, stream>>>(impbits, q, k, v, ctx, probs);
    // L3: Wo GEMV (4 rows/block)
    gemv_wo_kernel<<<DIM / 4, 256, 0, stream>>>(Wo, ctx, out);
}